// Round 1
// baseline (152.954 us; speedup 1.0000x reference)
//
#include <hip/hip_runtime.h>

namespace {

constexpr int BB = 64;
constexpr int DD = 196608;            // 3*256*256
constexpr float T_SCALE = 0.99f;      // 1 - 1/MAX_TIMESTEPS

// workspace layout in floats
constexpr int WS_CROSS = 0;           // 64*64
constexpr int WS_D2    = 4096;        // 64
constexpr int WS_W     = 4160;        // 64*64, stored transposed wT[j][i]
constexpr int WS_PART  = 8256;        // 1024 block partials
constexpr int NPART    = 1024;

__global__ void k_init(float* __restrict__ ws) {
  int idx = blockIdx.x * 256 + threadIdx.x;
  if (idx < WS_W) ws[idx] = 0.0f;     // zero cross + d2
}

// ---------------------------------------------------------------------------
// Phase 1: cross[i][j] = sum_k n[i][k]*d[j][k],  d2[j] = sum_k d[j][k]^2
// n[i][k] = noise + t_i*(data-noise).
// Grid: 512 blocks, each owns a contiguous K-chunk of 384 (6 subtiles of 64).
// LDS tiles stored k-major with quad XOR swizzle: element (row r, k) at word
//   k*64 + 4*((r>>2)^(k&15)) + (r&3)   -> b128 GEMM reads conflict-free.
// Each wave computes one 32x32 quadrant (8x8 lanes, 4x4 regs/lane).
// ---------------------------------------------------------------------------
__global__ __launch_bounds__(256) void k_cross(
    const float* __restrict__ data, const float* __restrict__ noise,
    const float* __restrict__ times, float* __restrict__ ws) {
  __shared__ __align__(16) float dT[4096];
  __shared__ __align__(16) float nT[4096];
  __shared__ float tls[64];

  const int t = threadIdx.x;
  if (t < 64) tls[t] = times[t] * T_SCALE;

  const int w  = t >> 6;
  const int l  = t & 63;
  const int Qa = ((w >> 1) << 3) + (l >> 3);   // i-quad index 0..15
  const int Qb = ((w & 1) << 3) + (l & 7);     // j-quad index 0..15
  const int q  = t & 15;                       // staging k-quad
  const int rr = t >> 4;                       // staging base row 0..15

  float acc[4][4];
#pragma unroll
  for (int a = 0; a < 4; ++a)
#pragma unroll
    for (int b = 0; b < 4; ++b) acc[a][b] = 0.0f;
  float d2p[4] = {0.f, 0.f, 0.f, 0.f};

  const int chunk0 = blockIdx.x * 384;
  for (int s = 0; s < 6; ++s) {
    const int k0 = chunk0 + (s << 6);
    __syncthreads();   // also covers tls init on s==0
#pragma unroll
    for (int it = 0; it < 4; ++it) {
      const int r = rr + (it << 4);
      const float4 dv = *(const float4*)(data  + (size_t)r * DD + k0 + (q << 2));
      const float4 zv = *(const float4*)(noise + (size_t)r * DD + k0 + (q << 2));
      const float tr = tls[r];
      float4 nv;
      nv.x = zv.x + tr * (dv.x - zv.x);
      nv.y = zv.y + tr * (dv.y - zv.y);
      nv.z = zv.z + tr * (dv.z - zv.z);
      nv.w = zv.w + tr * (dv.w - zv.w);
      d2p[it] += dv.x * dv.x + dv.y * dv.y + dv.z * dv.z + dv.w * dv.w;
      const int rq = r >> 2, rm = r & 3;
      const float* dp = (const float*)&dv;
      const float* np = (const float*)&nv;
#pragma unroll
      for (int e = 0; e < 4; ++e) {
        const int k = (q << 2) + e;
        const int word = (k << 6) + ((rq ^ (k & 15)) << 2) + rm;
        dT[word] = dp[e];
        nT[word] = np[e];
      }
    }
    __syncthreads();
#pragma unroll 8
    for (int k = 0; k < 64; ++k) {
      const int sw = k & 15;
      const float4 av = *(const float4*)(nT + (k << 6) + ((Qa ^ sw) << 2));
      const float4 bv = *(const float4*)(dT + (k << 6) + ((Qb ^ sw) << 2));
      const float* ap = (const float*)&av;
      const float* bp = (const float*)&bv;
#pragma unroll
      for (int ii = 0; ii < 4; ++ii)
#pragma unroll
        for (int jj = 0; jj < 4; ++jj)
          acc[ii][jj] = fmaf(ap[ii], bp[jj], acc[ii][jj]);
    }
  }

  // d2: reduce across the 16 staging k-quad lanes (same row group)
#pragma unroll
  for (int it = 0; it < 4; ++it) {
    float v = d2p[it];
    v += __shfl_xor(v, 1);
    v += __shfl_xor(v, 2);
    v += __shfl_xor(v, 4);
    v += __shfl_xor(v, 8);
    if ((l & 15) == 0) atomicAdd(ws + WS_D2 + rr + (it << 4), v);
  }
  // cross partial accumulation
#pragma unroll
  for (int ii = 0; ii < 4; ++ii)
#pragma unroll
    for (int jj = 0; jj < 4; ++jj)
      atomicAdd(ws + WS_CROSS + ((Qa << 2) + ii) * 64 + (Qb << 2) + jj,
                acc[ii][jj]);
}

// ---------------------------------------------------------------------------
// Phase 2: row softmax. n2 term is constant per row -> dropped.
// logit_ij = (2*t_i*cross_ij - t_i^2*d2_j) / (2*var_i)
// Writes weights transposed: wT[j][i].
// ---------------------------------------------------------------------------
__global__ void k_softmax(const float* __restrict__ times, float* __restrict__ ws) {
  const int i = blockIdx.x;
  const int j = threadIdx.x;
  const double t = (double)(times[i] * T_SCALE);
  const double omt = 1.0 - t;
  const double var = omt * omt + 1e-8;
  const double inv2v = 1.0 / (2.0 * var);
  const double c  = (double)ws[WS_CROSS + (i << 6) + j];
  const double d2 = (double)ws[WS_D2 + j];
  const double lg = (2.0 * t * c - t * t * d2) * inv2v;
  double m = lg;
#pragma unroll
  for (int msk = 1; msk <= 32; msk <<= 1) m = fmax(m, __shfl_xor(m, msk));
  const double e = exp(lg - m);
  double ssum = e;
#pragma unroll
  for (int msk = 1; msk <= 32; msk <<= 1) ssum += __shfl_xor(ssum, msk);
  ws[WS_W + (j << 6) + i] = (float)(e / ssum);
}

// ---------------------------------------------------------------------------
// Phase 3: mix = w @ d_flat fused with loss epilogue.
// loss_elem = 0.5*((pm-fc)^2 + pv*plv + u^2 - fc^2), u = (mix-n)/(1-t+eps)
// Grid: 1024 blocks x 3 k-tiles of 64. Thread = (ty i-quad, tx k-quad), 4x4.
// ---------------------------------------------------------------------------
__global__ __launch_bounds__(256) void k_mixloss(
    const float* __restrict__ data, const float* __restrict__ noise,
    const float* __restrict__ pmean, const float* __restrict__ plogv,
    const float* __restrict__ times, const float* __restrict__ ws,
    float* __restrict__ partials) {
  __shared__ __align__(16) float wT[4096];
  __shared__ __align__(16) float dt[4096];
  __shared__ float tls[64];
  __shared__ float red[4];

  const int t = threadIdx.x;
#pragma unroll
  for (int r = 0; r < 4; ++r) {
    const int word = (r << 10) + (t << 2);
    *(float4*)(wT + word) = *(const float4*)(ws + WS_W + word);
  }
  if (t < 64) tls[t] = times[t] * T_SCALE;

  const int tx = t & 15, ty = t >> 4;
  float lsum = 0.0f;

  for (int s = 0; s < 3; ++s) {
    const int k0 = (blockIdx.x * 3 + s) << 6;
    __syncthreads();   // protects prior-tile reads + (s==0) wT/tls init
#pragma unroll
    for (int it = 0; it < 4; ++it) {
      const int r = ty + (it << 4);
      *(float4*)(dt + (r << 6) + (tx << 2)) =
          *(const float4*)(data + (size_t)r * DD + k0 + (tx << 2));
    }
    __syncthreads();

    float mix[4][4];
#pragma unroll
    for (int a = 0; a < 4; ++a)
#pragma unroll
      for (int b = 0; b < 4; ++b) mix[a][b] = 0.0f;
#pragma unroll 8
    for (int j = 0; j < 64; ++j) {
      const float4 av = *(const float4*)(wT + (j << 6) + (ty << 2));
      const float4 bv = *(const float4*)(dt + (j << 6) + (tx << 2));
      const float* ap = (const float*)&av;
      const float* bp = (const float*)&bv;
#pragma unroll
      for (int ii = 0; ii < 4; ++ii)
#pragma unroll
        for (int kk = 0; kk < 4; ++kk)
          mix[ii][kk] = fmaf(ap[ii], bp[kk], mix[ii][kk]);
    }

#pragma unroll
    for (int ii = 0; ii < 4; ++ii) {
      const int i = (ty << 2) + ii;
      const float ti = tls[i];
      const float inv1mt = 1.0f / (1.0f - ti + 1e-8f);
      const size_t base = (size_t)i * DD + k0 + (tx << 2);
      const float4 dv   = *(const float4*)(dt + (i << 6) + (tx << 2));
      const float4 zv   = *(const float4*)(noise + base);
      const float4 pmv  = *(const float4*)(pmean + base);
      const float4 plvv = *(const float4*)(plogv + base);
      const float* dp  = (const float*)&dv;
      const float* zp  = (const float*)&zv;
      const float* pmp = (const float*)&pmv;
      const float* plp = (const float*)&plvv;
#pragma unroll
      for (int e = 0; e < 4; ++e) {
        const float dd = dp[e], zz = zp[e], pme = pmp[e], pl = plp[e];
        const float fc = dd - zz;
        const float nn = zz + ti * (dd - zz);
        const float u  = (mix[ii][e] - nn) * inv1mt;
        const float pv = expf(pl);
        const float dpm = pme - fc;
        lsum += 0.5f * (dpm * dpm + pv * pl + u * u - fc * fc);
      }
    }
  }

  float v = lsum;
#pragma unroll
  for (int m = 1; m <= 32; m <<= 1) v += __shfl_xor(v, m);
  if ((t & 63) == 0) red[t >> 6] = v;
  __syncthreads();
  if (t == 0) partials[blockIdx.x] = red[0] + red[1] + red[2] + red[3];
}

__global__ void k_final(const float* __restrict__ partials, float* __restrict__ out) {
  const int t = threadIdx.x;
  const float4 v = *(const float4*)(partials + (t << 2));
  double s = (double)v.x + (double)v.y + (double)v.z + (double)v.w;
#pragma unroll
  for (int m = 1; m <= 32; m <<= 1) s += __shfl_xor(s, m);
  __shared__ double rs[4];
  if ((t & 63) == 0) rs[t >> 6] = s;
  __syncthreads();
  if (t == 0) {
    const double total = rs[0] + rs[1] + rs[2] + rs[3];
    out[0] = (float)(total / (double)((size_t)BB * DD));
  }
}

}  // namespace

extern "C" void kernel_launch(void* const* d_in, const int* in_sizes, int n_in,
                              void* d_out, int out_size, void* d_ws, size_t ws_size,
                              hipStream_t stream) {
  const float* data  = (const float*)d_in[0];
  const float* noise = (const float*)d_in[1];
  const float* times = (const float*)d_in[2];
  const float* pmean = (const float*)d_in[3];
  const float* plogv = (const float*)d_in[4];
  float* out = (float*)d_out;
  float* ws  = (float*)d_ws;

  k_init<<<dim3(17), dim3(256), 0, stream>>>(ws);
  k_cross<<<dim3(512), dim3(256), 0, stream>>>(data, noise, times, ws);
  k_softmax<<<dim3(64), dim3(64), 0, stream>>>(times, ws);
  k_mixloss<<<dim3(1024), dim3(256), 0, stream>>>(data, noise, pmean, plogv,
                                                  times, ws, ws + WS_PART);
  k_final<<<dim3(1), dim3(256), 0, stream>>>(ws + WS_PART, out);
}

// Round 2
// 110.942 us; speedup vs baseline: 1.3787x; 1.3787x over previous
//
#include <hip/hip_runtime.h>

namespace {

constexpr int BB = 64;
constexpr int DD = 196608;            // 3*256*256
constexpr float T_SCALE = 0.99f;      // 1 - 1/MAX_TIMESTEPS

// workspace layout in floats
constexpr int WS_CROSS = 0;           // 64*64
constexpr int WS_D2    = 4096;        // 64
constexpr int WS_W     = 4160;        // 64*64, stored transposed wT[j][i]
constexpr int WS_PART  = 8256;        // 1024 block partials (loss)
constexpr int WS_BIGP  = 9280;        // NB * PSTRIDE cross/d2 partials
constexpr int PSTRIDE  = 4160;        // 4096 cross + 64 d2 per block

__global__ void k_init(float* __restrict__ ws) {
  int idx = blockIdx.x * 256 + threadIdx.x;
  if (idx < WS_W) ws[idx] = 0.0f;     // zero cross + d2
}

// ---------------------------------------------------------------------------
// Phase 1: cross[i][j] = sum_k n[i][k]*d[j][k],  d2[j] = sum_k d[j][k]^2
// n[i][k] = noise + t_i*(data-noise).
// Grid: NB blocks, each owns a contiguous K-chunk of SUBT*64.
// Register-staged prefetch: subtile s+1's global loads issue before the
// GEMM on subtile s; LDS write happens after the read barrier.
// LDS tiles k-major with quad XOR swizzle: (row r, k) at word
//   k*64 + 4*((r>>2)^(k&15)) + (r&3)  -> b128 GEMM reads conflict-free.
// Each wave computes one 32x32 quadrant (8x8 lanes, 4x4 regs/lane).
// ATOMIC=false: per-block partials streamed to bigp (no global atomics).
// ---------------------------------------------------------------------------
template <int SUBT, bool ATOMIC>
__global__ __launch_bounds__(256) void k_cross(
    const float* __restrict__ data, const float* __restrict__ noise,
    const float* __restrict__ times, float* __restrict__ ws,
    float* __restrict__ bigp) {
  __shared__ __align__(16) float dT[4096];
  __shared__ __align__(16) float nT[4096];
  __shared__ float tls[64];

  const int t = threadIdx.x;
  if (t < 64) tls[t] = times[t] * T_SCALE;

  const int w  = t >> 6;
  const int l  = t & 63;
  const int Qa = ((w >> 1) << 3) + (l >> 3);   // i-quad index 0..15
  const int Qb = ((w & 1) << 3) + (l & 7);     // j-quad index 0..15
  const int q  = t & 15;                       // staging k-quad
  const int rr = t >> 4;                       // staging base row 0..15

  float acc[4][4];
#pragma unroll
  for (int a = 0; a < 4; ++a)
#pragma unroll
    for (int b = 0; b < 4; ++b) acc[a][b] = 0.0f;
  float d2p[4] = {0.f, 0.f, 0.f, 0.f};

  const int chunk0 = blockIdx.x * (SUBT << 6);

  float4 dv[4], zv[4];   // in-flight staging registers

  auto LOAD = [&](int s) {
#pragma unroll
    for (int it = 0; it < 4; ++it) {
      const int r = rr + (it << 4);
      const size_t off = (size_t)r * DD + chunk0 + (s << 6) + (q << 2);
      dv[it] = *(const float4*)(data + off);
      zv[it] = *(const float4*)(noise + off);
    }
  };
  auto WRITE = [&]() {
#pragma unroll
    for (int it = 0; it < 4; ++it) {
      const int r = rr + (it << 4);
      const float tr = tls[r];
      float4 nv;
      nv.x = zv[it].x + tr * (dv[it].x - zv[it].x);
      nv.y = zv[it].y + tr * (dv[it].y - zv[it].y);
      nv.z = zv[it].z + tr * (dv[it].z - zv[it].z);
      nv.w = zv[it].w + tr * (dv[it].w - zv[it].w);
      d2p[it] += dv[it].x * dv[it].x + dv[it].y * dv[it].y +
                 dv[it].z * dv[it].z + dv[it].w * dv[it].w;
      const int rq = r >> 2, rm = r & 3;
      const float* dp = (const float*)&dv[it];
      const float* np = (const float*)&nv;
#pragma unroll
      for (int e = 0; e < 4; ++e) {
        const int k = (q << 2) + e;
        const int word = (k << 6) + ((rq ^ (k & 15)) << 2) + rm;
        dT[word] = dp[e];
        nT[word] = np[e];
      }
    }
  };

  // prologue: stage subtile 0
  LOAD(0);
  __syncthreads();               // tls ready
  WRITE();

  for (int s = 0; s < SUBT; ++s) {
    if (s + 1 < SUBT) LOAD(s + 1);
    __syncthreads();             // tile s writes visible
#pragma unroll 8
    for (int k = 0; k < 64; ++k) {
      const int sw = k & 15;
      const float4 av = *(const float4*)(nT + (k << 6) + ((Qa ^ sw) << 2));
      const float4 bv = *(const float4*)(dT + (k << 6) + ((Qb ^ sw) << 2));
      const float* ap = (const float*)&av;
      const float* bp = (const float*)&bv;
#pragma unroll
      for (int ii = 0; ii < 4; ++ii)
#pragma unroll
        for (int jj = 0; jj < 4; ++jj)
          acc[ii][jj] = fmaf(ap[ii], bp[jj], acc[ii][jj]);
    }
    __syncthreads();             // tile s reads done
    if (s + 1 < SUBT) WRITE();
  }

  // d2: reduce across the 16 staging k-quad lanes (same row group)
#pragma unroll
  for (int it = 0; it < 4; ++it) {
    float v = d2p[it];
    v += __shfl_xor(v, 1);
    v += __shfl_xor(v, 2);
    v += __shfl_xor(v, 4);
    v += __shfl_xor(v, 8);
    if ((l & 15) == 0) {
      if (ATOMIC)
        atomicAdd(ws + WS_D2 + rr + (it << 4), v);
      else
        bigp[(size_t)blockIdx.x * PSTRIDE + 4096 + rr + (it << 4)] = v;
    }
  }

  if (ATOMIC) {
#pragma unroll
    for (int ii = 0; ii < 4; ++ii)
#pragma unroll
      for (int jj = 0; jj < 4; ++jj)
        atomicAdd(ws + WS_CROSS + ((Qa << 2) + ii) * 64 + (Qb << 2) + jj,
                  acc[ii][jj]);
  } else {
    // stage acc into dT (post-loop barrier already passed), stream out
#pragma unroll
    for (int ii = 0; ii < 4; ++ii)
#pragma unroll
      for (int jj = 0; jj < 4; ++jj)
        dT[((Qa << 2) + ii) * 64 + (Qb << 2) + jj] = acc[ii][jj];
    __syncthreads();
    float* dst = bigp + (size_t)blockIdx.x * PSTRIDE;
#pragma unroll
    for (int e = 0; e < 4; ++e)
      *(float4*)(dst + (t << 4) + (e << 2)) =
          *(const float4*)(dT + (t << 4) + (e << 2));
  }
}

// Fold NB per-block partials into ws[0..4160). 8-way atomic contention only.
__global__ void k_reduce(const float* __restrict__ bigp, float* __restrict__ ws,
                         int nb) {
  const int idx = blockIdx.x * 64 + threadIdx.x;   // grid.x=65 -> 0..4159
  const int per = nb >> 3;                         // grid.y=8
  const size_t b0 = (size_t)blockIdx.y * per;
  float s = 0.f;
#pragma unroll 4
  for (int b = 0; b < per; ++b)
    s += bigp[(b0 + b) * PSTRIDE + idx];
  atomicAdd(ws + idx, s);
}

// ---------------------------------------------------------------------------
// Phase 2: row softmax. n2 term is constant per row -> dropped.
// logit_ij = (2*t_i*cross_ij - t_i^2*d2_j) / (2*var_i)
// Writes weights transposed: wT[j][i].
// ---------------------------------------------------------------------------
__global__ void k_softmax(const float* __restrict__ times, float* __restrict__ ws) {
  const int i = blockIdx.x;
  const int j = threadIdx.x;
  const double t = (double)(times[i] * T_SCALE);
  const double omt = 1.0 - t;
  const double var = omt * omt + 1e-8;
  const double inv2v = 1.0 / (2.0 * var);
  const double c  = (double)ws[WS_CROSS + (i << 6) + j];
  const double d2 = (double)ws[WS_D2 + j];
  const double lg = (2.0 * t * c - t * t * d2) * inv2v;
  double m = lg;
#pragma unroll
  for (int msk = 1; msk <= 32; msk <<= 1) m = fmax(m, __shfl_xor(m, msk));
  const double e = exp(lg - m);
  double ssum = e;
#pragma unroll
  for (int msk = 1; msk <= 32; msk <<= 1) ssum += __shfl_xor(ssum, msk);
  ws[WS_W + (j << 6) + i] = (float)(e / ssum);
}

// ---------------------------------------------------------------------------
// Phase 3: mix = w @ d_flat fused with loss epilogue.
// loss_elem = 0.5*((pm-fc)^2 + pv*plv + u^2 - fc^2), u = (mix-n)/(1-t+eps)
// Grid: 1024 blocks x 3 k-tiles of 64. Thread = (ty i-quad, tx k-quad), 4x4.
// ---------------------------------------------------------------------------
__global__ __launch_bounds__(256) void k_mixloss(
    const float* __restrict__ data, const float* __restrict__ noise,
    const float* __restrict__ pmean, const float* __restrict__ plogv,
    const float* __restrict__ times, const float* __restrict__ ws,
    float* __restrict__ partials) {
  __shared__ __align__(16) float wT[4096];
  __shared__ __align__(16) float dt[4096];
  __shared__ float tls[64];
  __shared__ float red[4];

  const int t = threadIdx.x;
#pragma unroll
  for (int r = 0; r < 4; ++r) {
    const int word = (r << 10) + (t << 2);
    *(float4*)(wT + word) = *(const float4*)(ws + WS_W + word);
  }
  if (t < 64) tls[t] = times[t] * T_SCALE;

  const int tx = t & 15, ty = t >> 4;
  float lsum = 0.0f;

  for (int s = 0; s < 3; ++s) {
    const int k0 = (blockIdx.x * 3 + s) << 6;
    __syncthreads();   // protects prior-tile reads + (s==0) wT/tls init
#pragma unroll
    for (int it = 0; it < 4; ++it) {
      const int r = ty + (it << 4);
      *(float4*)(dt + (r << 6) + (tx << 2)) =
          *(const float4*)(data + (size_t)r * DD + k0 + (tx << 2));
    }
    __syncthreads();

    float mix[4][4];
#pragma unroll
    for (int a = 0; a < 4; ++a)
#pragma unroll
      for (int b = 0; b < 4; ++b) mix[a][b] = 0.0f;
#pragma unroll 8
    for (int j = 0; j < 64; ++j) {
      const float4 av = *(const float4*)(wT + (j << 6) + (ty << 2));
      const float4 bv = *(const float4*)(dt + (j << 6) + (tx << 2));
      const float* ap = (const float*)&av;
      const float* bp = (const float*)&bv;
#pragma unroll
      for (int ii = 0; ii < 4; ++ii)
#pragma unroll
        for (int kk = 0; kk < 4; ++kk)
          mix[ii][kk] = fmaf(ap[ii], bp[kk], mix[ii][kk]);
    }

#pragma unroll
    for (int ii = 0; ii < 4; ++ii) {
      const int i = (ty << 2) + ii;
      const float ti = tls[i];
      const float inv1mt = 1.0f / (1.0f - ti + 1e-8f);
      const size_t base = (size_t)i * DD + k0 + (tx << 2);
      const float4 dv   = *(const float4*)(dt + (i << 6) + (tx << 2));
      const float4 zv   = *(const float4*)(noise + base);
      const float4 pmv  = *(const float4*)(pmean + base);
      const float4 plvv = *(const float4*)(plogv + base);
      const float* dp  = (const float*)&dv;
      const float* zp  = (const float*)&zv;
      const float* pmp = (const float*)&pmv;
      const float* plp = (const float*)&plvv;
#pragma unroll
      for (int e = 0; e < 4; ++e) {
        const float dd = dp[e], zz = zp[e], pme = pmp[e], pl = plp[e];
        const float fc = dd - zz;
        const float nn = zz + ti * (dd - zz);
        const float u  = (mix[ii][e] - nn) * inv1mt;
        const float pv = expf(pl);
        const float dpm = pme - fc;
        lsum += 0.5f * (dpm * dpm + pv * pl + u * u - fc * fc);
      }
    }
  }

  float v = lsum;
#pragma unroll
  for (int m = 1; m <= 32; m <<= 1) v += __shfl_xor(v, m);
  if ((t & 63) == 0) red[t >> 6] = v;
  __syncthreads();
  if (t == 0) partials[blockIdx.x] = red[0] + red[1] + red[2] + red[3];
}

__global__ void k_final(const float* __restrict__ partials, float* __restrict__ out) {
  const int t = threadIdx.x;
  const float4 v = *(const float4*)(partials + (t << 2));
  double s = (double)v.x + (double)v.y + (double)v.z + (double)v.w;
#pragma unroll
  for (int m = 1; m <= 32; m <<= 1) s += __shfl_xor(s, m);
  __shared__ double rs[4];
  if ((t & 63) == 0) rs[t >> 6] = s;
  __syncthreads();
  if (t == 0) {
    const double total = rs[0] + rs[1] + rs[2] + rs[3];
    out[0] = (float)(total / (double)((size_t)BB * DD));
  }
}

}  // namespace

extern "C" void kernel_launch(void* const* d_in, const int* in_sizes, int n_in,
                              void* d_out, int out_size, void* d_ws, size_t ws_size,
                              hipStream_t stream) {
  const float* data  = (const float*)d_in[0];
  const float* noise = (const float*)d_in[1];
  const float* times = (const float*)d_in[2];
  const float* pmean = (const float*)d_in[3];
  const float* plogv = (const float*)d_in[4];
  float* out = (float*)d_out;
  float* ws  = (float*)d_ws;
  float* bigp = ws + WS_BIGP;

  auto fits = [&](int nb) {
    return ws_size >= ((size_t)WS_BIGP + (size_t)nb * PSTRIDE) * sizeof(float);
  };

  k_init<<<dim3(17), dim3(256), 0, stream>>>(ws);
  if (fits(1024)) {
    k_cross<3, false><<<dim3(1024), dim3(256), 0, stream>>>(data, noise, times, ws, bigp);
    k_reduce<<<dim3(65, 8), dim3(64), 0, stream>>>(bigp, ws, 1024);
  } else if (fits(512)) {
    k_cross<6, false><<<dim3(512), dim3(256), 0, stream>>>(data, noise, times, ws, bigp);
    k_reduce<<<dim3(65, 8), dim3(64), 0, stream>>>(bigp, ws, 512);
  } else if (fits(256)) {
    k_cross<12, false><<<dim3(256), dim3(256), 0, stream>>>(data, noise, times, ws, bigp);
    k_reduce<<<dim3(65, 8), dim3(64), 0, stream>>>(bigp, ws, 256);
  } else {
    k_cross<6, true><<<dim3(512), dim3(256), 0, stream>>>(data, noise, times, ws, bigp);
  }
  k_softmax<<<dim3(64), dim3(64), 0, stream>>>(times, ws);
  k_mixloss<<<dim3(1024), dim3(256), 0, stream>>>(data, noise, pmean, plogv,
                                                  times, ws, ws + WS_PART);
  k_final<<<dim3(1), dim3(256), 0, stream>>>(ws + WS_PART, out);
}

// Round 3
// 100.424 us; speedup vs baseline: 1.5231x; 1.1047x over previous
//
#include <hip/hip_runtime.h>

namespace {

constexpr int BB = 64;
constexpr int DDIM = 196608;          // 3*256*256
constexpr float T_SCALE = 0.99f;      // 1 - 1/MAX_TIMESTEPS

// workspace layout in floats (ws[idx] mirrors per-block bigp layout for idx<NRED)
constexpr int WS_CROSS = 0;           // 64*64  cross[i][j] = n_i . d_j
constexpr int WS_DDG   = 4096;        // 64*64  DD[i][j] = d_i . d_j
constexpr int WS_D2    = 8192;        // 64
constexpr int WS_N2    = 8256;        // 64
constexpr int WS_ELEM  = 8320;        // 1 (elementwise loss total)
constexpr int NRED     = 8321;        // reduce-target count
constexpr int WS_U2    = 8384;        // 64 per-row sum(u^2)
constexpr int WS_BIGP  = 8448;        // NB * PSTRIDE partials
constexpr int PSTRIDE  = 8384;

__global__ void k_init(float* __restrict__ ws) {
  int idx = blockIdx.x * 256 + threadIdx.x;
  if (idx < NRED) ws[idx] = 0.0f;
}

// ---------------------------------------------------------------------------
// Phase 1: two Grams + row sums + fused elementwise loss.
//   cross[i][j] = sum_k n_i[k] d_j[k],  DD[i][j] = sum_k d_i[k] d_j[k]
//   d2[i] = |d_i|^2, n2[i] = |n_i|^2,  n = z + t(d-z)
//   elem  = sum 0.5[(pm-fc)^2 + exp(plv)*plv - fc^2],  fc = d-z
// Waves 0,1 compute cross (a-side nT), waves 2,3 compute DD (a-side dT);
// wave parity picks k-half [0,32)/[32,64) of each 64-wide subtile.
// Each lane: 8x8 register tile (li=l>>3 rows 8li.., lj=l&7 cols 8lj..).
// LDS tiles k-major, quad XOR swizzle: (row r, k) word = k*64+((r>>2)^(k&15))*4+(r&3).
// Register prefetch: next subtile's 16 float4 loads issued before current GEMM.
// ---------------------------------------------------------------------------
template <int SUBT, bool ATOMIC>
__global__ __launch_bounds__(256, 2) void k_cross(
    const float* __restrict__ data, const float* __restrict__ noise,
    const float* __restrict__ pmean, const float* __restrict__ plogv,
    const float* __restrict__ times, float* __restrict__ ws,
    float* __restrict__ bigp) {
  __shared__ __align__(16) float dT[4096];
  __shared__ __align__(16) float nT[4096];
  __shared__ float tls[64];
  __shared__ float esm[4];

  const int t = threadIdx.x;
  if (t < 64) tls[t] = times[t] * T_SCALE;

  const int w  = t >> 6;
  const int l  = t & 63;
  const int li = l >> 3;               // row-octet 0..7
  const int lj = l & 7;                // col-octet 0..7
  const int q  = t & 15;               // staging k-quad
  const int rr = t >> 4;               // staging base row 0..15

  float acc[8][8];
#pragma unroll
  for (int a = 0; a < 8; ++a)
#pragma unroll
    for (int b = 0; b < 8; ++b) acc[a][b] = 0.0f;
  float d2p[4] = {0.f, 0.f, 0.f, 0.f};
  float n2p[4] = {0.f, 0.f, 0.f, 0.f};
  float eacc = 0.0f;

  const int chunk0 = blockIdx.x * (SUBT << 6);
  float4 dv[4], zv[4], pmv[4], lvv[4];

  auto LOAD = [&](int s) {
#pragma unroll
    for (int it = 0; it < 4; ++it) {
      const int r = rr + (it << 4);
      const size_t off = (size_t)r * DDIM + chunk0 + (s << 6) + (q << 2);
      dv[it]  = *(const float4*)(data  + off);
      zv[it]  = *(const float4*)(noise + off);
      pmv[it] = *(const float4*)(pmean + off);
      lvv[it] = *(const float4*)(plogv + off);
    }
  };
  auto WRITE = [&]() {
#pragma unroll
    for (int it = 0; it < 4; ++it) {
      const int r = rr + (it << 4);
      const float tr = tls[r];
      float4 nv;
      nv.x = zv[it].x + tr * (dv[it].x - zv[it].x);
      nv.y = zv[it].y + tr * (dv[it].y - zv[it].y);
      nv.z = zv[it].z + tr * (dv[it].z - zv[it].z);
      nv.w = zv[it].w + tr * (dv[it].w - zv[it].w);
      d2p[it] += dv[it].x * dv[it].x + dv[it].y * dv[it].y +
                 dv[it].z * dv[it].z + dv[it].w * dv[it].w;
      n2p[it] += nv.x * nv.x + nv.y * nv.y + nv.z * nv.z + nv.w * nv.w;
      const float* dp = (const float*)&dv[it];
      const float* zp = (const float*)&zv[it];
      const float* pp = (const float*)&pmv[it];
      const float* gp = (const float*)&lvv[it];
      const float* np = (const float*)&nv;
#pragma unroll
      for (int e = 0; e < 4; ++e) {
        const float fc = dp[e] - zp[e];
        const float dpm = pp[e] - fc;
        const float pl = gp[e];
        eacc += 0.5f * (dpm * dpm + __expf(pl) * pl - fc * fc);
      }
      const int rq = r >> 2, rm = r & 3;
#pragma unroll
      for (int e = 0; e < 4; ++e) {
        const int k = (q << 2) + e;
        const int word = (k << 6) + ((rq ^ (k & 15)) << 2) + rm;
        dT[word] = dp[e];
        nT[word] = np[e];
      }
    }
  };

  const float* aT  = (w < 2) ? nT : dT;   // wave-uniform operand select
  const int kbase  = (w & 1) << 5;

  LOAD(0);
  __syncthreads();               // tls ready
  WRITE();

  for (int s = 0; s < SUBT; ++s) {
    if (s + 1 < SUBT) LOAD(s + 1);
    __syncthreads();             // tile writes visible
#pragma unroll 4
    for (int kk = 0; kk < 32; ++kk) {
      const int k   = kbase + kk;
      const int kb  = k << 6;
      const int sw2 = (k & 15) << 2;
      const float4 a0 = *(const float4*)(aT + kb + ((li << 3) ^ sw2));
      const float4 a1 = *(const float4*)(aT + kb + (((li << 3) | 4) ^ sw2));
      const float4 b0 = *(const float4*)(dT + kb + ((lj << 3) ^ sw2));
      const float4 b1 = *(const float4*)(dT + kb + (((lj << 3) | 4) ^ sw2));
      const float a8[8] = {a0.x, a0.y, a0.z, a0.w, a1.x, a1.y, a1.z, a1.w};
      const float b8[8] = {b0.x, b0.y, b0.z, b0.w, b1.x, b1.y, b1.z, b1.w};
#pragma unroll
      for (int ii = 0; ii < 8; ++ii)
#pragma unroll
        for (int jj = 0; jj < 8; ++jj)
          acc[ii][jj] = fmaf(a8[ii], b8[jj], acc[ii][jj]);
    }
    __syncthreads();             // tile reads done
    if (s + 1 < SUBT) WRITE();
  }

  // ---- epilogue: cross-wave pair reduction into nT (cross) / dT (DD) ----
  float* outT = (w < 2) ? nT : dT;
  if ((w & 1) == 0) {
#pragma unroll
    for (int ii = 0; ii < 8; ++ii)
#pragma unroll
      for (int h = 0; h < 2; ++h) {
        float4 v;
        v.x = acc[ii][h * 4 + 0]; v.y = acc[ii][h * 4 + 1];
        v.z = acc[ii][h * 4 + 2]; v.w = acc[ii][h * 4 + 3];
        *(float4*)(outT + (((li << 3) + ii) << 6) + (lj << 3) + (h << 2)) = v;
      }
  }
  // d2/n2: reduce across 16 staging k-quad lanes (no LDS involved)
#pragma unroll
  for (int it = 0; it < 4; ++it) {
    float v1 = d2p[it], v2 = n2p[it];
    v1 += __shfl_xor(v1, 1); v2 += __shfl_xor(v2, 1);
    v1 += __shfl_xor(v1, 2); v2 += __shfl_xor(v2, 2);
    v1 += __shfl_xor(v1, 4); v2 += __shfl_xor(v2, 4);
    v1 += __shfl_xor(v1, 8); v2 += __shfl_xor(v2, 8);
    if ((l & 15) == 0) {
      const int r = rr + (it << 4);
      if (ATOMIC) {
        atomicAdd(ws + WS_D2 + r, v1);
        atomicAdd(ws + WS_N2 + r, v2);
      } else {
        bigp[(size_t)blockIdx.x * PSTRIDE + WS_D2 + r] = v1;
        bigp[(size_t)blockIdx.x * PSTRIDE + WS_N2 + r] = v2;
      }
    }
  }
  // elementwise-loss wave total
  float ev = eacc;
#pragma unroll
  for (int m = 1; m <= 32; m <<= 1) ev += __shfl_xor(ev, m);
  if (l == 0) esm[w] = ev;

  __syncthreads();               // stores from waves 0,2 + esm visible
  if (w & 1) {
#pragma unroll
    for (int ii = 0; ii < 8; ++ii)
#pragma unroll
      for (int h = 0; h < 2; ++h) {
        float* p = outT + (((li << 3) + ii) << 6) + (lj << 3) + (h << 2);
        float4 v = *(float4*)p;
        v.x += acc[ii][h * 4 + 0]; v.y += acc[ii][h * 4 + 1];
        v.z += acc[ii][h * 4 + 2]; v.w += acc[ii][h * 4 + 3];
        *(float4*)p = v;
      }
  }
  __syncthreads();               // tiles final

  if (ATOMIC) {
#pragma unroll
    for (int e = 0; e < 16; ++e) {
      atomicAdd(ws + WS_CROSS + (t << 4) + e, nT[(t << 4) + e]);
      atomicAdd(ws + WS_DDG   + (t << 4) + e, dT[(t << 4) + e]);
    }
    if (t == 0) atomicAdd(ws + WS_ELEM, esm[0] + esm[1] + esm[2] + esm[3]);
  } else {
    float* dst = bigp + (size_t)blockIdx.x * PSTRIDE;
#pragma unroll
    for (int e = 0; e < 4; ++e) {
      *(float4*)(dst + (t << 4) + (e << 2)) =
          *(const float4*)(nT + (t << 4) + (e << 2));
      *(float4*)(dst + WS_DDG + (t << 4) + (e << 2)) =
          *(const float4*)(dT + (t << 4) + (e << 2));
    }
    if (t == 0) dst[WS_ELEM] = esm[0] + esm[1] + esm[2] + esm[3];
  }
}

// Fold NB per-block partials into ws[0..NRED). 8-way atomic contention only.
__global__ void k_reduce(const float* __restrict__ bigp, float* __restrict__ ws,
                         int nb) {
  const int idx = blockIdx.x * 64 + threadIdx.x;
  if (idx >= NRED) return;
  const int per = nb >> 3;
  const size_t b0 = (size_t)blockIdx.y * per;
  float s = 0.f;
#pragma unroll 4
  for (int b = 0; b < per; ++b)
    s += bigp[(b0 + b) * PSTRIDE + idx];
  atomicAdd(ws + idx, s);
}

// ---------------------------------------------------------------------------
// Phase 2 (tiny): per row i — softmax over logits, then Gram-space u^2 sum:
//   logit_j = (2 t cross_ij - t^2 d2_j) / (2 var_i)   (n2 row-const dropped)
//   sum_k u^2 = (w^T DD w - 2 w.cross_i + n2_i) / (1 - t + eps)^2
// ---------------------------------------------------------------------------
__global__ void k_small(const float* __restrict__ times, float* __restrict__ ws) {
  const int i = blockIdx.x;
  const int j = threadIdx.x;
  const double t = (double)(times[i] * T_SCALE);
  const double omt = 1.0 - t;
  const double var = omt * omt + 1e-8;
  const double inv2v = 1.0 / (2.0 * var);
  const double c  = (double)ws[WS_CROSS + (i << 6) + j];
  const double lg = (2.0 * t * c - t * t * (double)ws[WS_D2 + j]) * inv2v;
  double m = lg;
#pragma unroll
  for (int msk = 1; msk <= 32; msk <<= 1) m = fmax(m, __shfl_xor(m, msk));
  const double e = exp(lg - m);
  double S = e;
#pragma unroll
  for (int msk = 1; msk <= 32; msk <<= 1) S += __shfl_xor(S, msk);
  const double wgt = e / S;

  __shared__ double wsh[64];
  wsh[j] = wgt;
  __syncthreads();
  double inner = 0.0;
#pragma unroll 8
  for (int j2 = 0; j2 < 64; ++j2)
    inner += wsh[j2] * (double)ws[WS_DDG + (j << 6) + j2];
  double s1 = wgt * inner;
  double s2 = wgt * c;
#pragma unroll
  for (int msk = 1; msk <= 32; msk <<= 1) {
    s1 += __shfl_xor(s1, msk);
    s2 += __shfl_xor(s2, msk);
  }
  if (j == 0) {
    const double den = omt + 1e-8;
    ws[WS_U2 + i] =
        (float)((s1 - 2.0 * s2 + (double)ws[WS_N2 + i]) / (den * den));
  }
}

__global__ void k_final(const float* __restrict__ ws, float* __restrict__ out) {
  const int t = threadIdx.x;
  double v = 0.5 * (double)ws[WS_U2 + t];
  if (t == 0) v += (double)ws[WS_ELEM];
#pragma unroll
  for (int m = 1; m <= 32; m <<= 1) v += __shfl_xor(v, m);
  if (t == 0) out[0] = (float)(v / (double)((size_t)BB * DDIM));
}

}  // namespace

extern "C" void kernel_launch(void* const* d_in, const int* in_sizes, int n_in,
                              void* d_out, int out_size, void* d_ws, size_t ws_size,
                              hipStream_t stream) {
  const float* data  = (const float*)d_in[0];
  const float* noise = (const float*)d_in[1];
  const float* times = (const float*)d_in[2];
  const float* pmean = (const float*)d_in[3];
  const float* plogv = (const float*)d_in[4];
  float* out = (float*)d_out;
  float* ws  = (float*)d_ws;
  float* bigp = ws + WS_BIGP;

  auto fits = [&](int nb) {
    return ws_size >= ((size_t)WS_BIGP + (size_t)nb * PSTRIDE) * sizeof(float);
  };

  k_init<<<dim3(33), dim3(256), 0, stream>>>(ws);
  if (fits(1024)) {
    k_cross<3, false><<<dim3(1024), dim3(256), 0, stream>>>(
        data, noise, pmean, plogv, times, ws, bigp);
    k_reduce<<<dim3(131, 8), dim3(64), 0, stream>>>(bigp, ws, 1024);
  } else if (fits(512)) {
    k_cross<6, false><<<dim3(512), dim3(256), 0, stream>>>(
        data, noise, pmean, plogv, times, ws, bigp);
    k_reduce<<<dim3(131, 8), dim3(64), 0, stream>>>(bigp, ws, 512);
  } else if (fits(256)) {
    k_cross<12, false><<<dim3(256), dim3(256), 0, stream>>>(
        data, noise, pmean, plogv, times, ws, bigp);
    k_reduce<<<dim3(131, 8), dim3(64), 0, stream>>>(bigp, ws, 256);
  } else {
    k_cross<6, true><<<dim3(512), dim3(256), 0, stream>>>(
        data, noise, pmean, plogv, times, ws, bigp);
  }
  k_small<<<dim3(64), dim3(64), 0, stream>>>(times, ws);
  k_final<<<dim3(1), dim3(64), 0, stream>>>(ws, out);
}